// Round 5
// baseline (297.508 us; speedup 1.0000x reference)
//
#include <hip/hip_runtime.h>
#include <hip/hip_bf16.h>

typedef _Float16 half_t;
typedef _Float16 h8 __attribute__((ext_vector_type(8)));   // MFMA A/B frag (4 VGPRs)
typedef _Float16 h4 __attribute__((ext_vector_type(4)));   // 8B chunk / K=16 frag
typedef float f32x4 __attribute__((ext_vector_type(4)));   // MFMA C/D frag
typedef float f4 __attribute__((ext_vector_type(4)));

#define DEVI __device__ __forceinline__

constexpr int NB = 2;         // batch
constexpr int S  = 2048;      // seq len
constexpr int DM = 1024;      // model dim
constexpr int NH = 16;        // heads
constexpr int HD = 64;        // head dim
constexpr long M = (long)NB * S;   // 4096 tokens
constexpr int N3 = 3 * DM;         // 3072 qkv cols

DEVI f32x4 mfma16(h8 a, h8 b, f32x4 c) {
  return __builtin_amdgcn_mfma_f32_16x16x32_f16(a, b, c, 0, 0, 0);
}
DEVI f32x4 mfma16h(h4 a, h4 b, f32x4 c) {          // K=16 legacy shape
  return __builtin_amdgcn_mfma_f32_16x16x16f16(a, b, c, 0, 0, 0);
}
DEVI h8 ld8h(const half_t* p) { return *(const h8*)p; }

#if __has_builtin(__builtin_amdgcn_exp2f)
DEVI float ex2(float x) { return __builtin_amdgcn_exp2f(x); }
#else
DEVI float ex2(float x) { float r; asm("v_exp_f32 %0, %1" : "=v"(r) : "v"(x)); return r; }
#endif

DEVI void gl_lds16(const half_t* g, half_t* l) {
  __builtin_amdgcn_global_load_lds(
      (const __attribute__((address_space(1))) void*)g,
      (__attribute__((address_space(3))) void*)l, 16, 0, 0);
}

// ---------------- H fp32 -> fp16 (4M elems, 8/thread) ----------------
__global__ void convert_h(const float* __restrict__ in, half_t* __restrict__ out) {
  const long i = ((long)blockIdx.x * 256 + threadIdx.x) * 8;
  const f4 a = *(const f4*)(in + i), b = *(const f4*)(in + i + 4);
  h8 r;
  #pragma unroll
  for (int k = 0; k < 4; k++) { r[k] = (half_t)a[k]; r[4 + k] = (half_t)b[k]; }
  *(h8*)(out + i) = r;
}

// ------- W transpose+convert: fp32 (1024 x 3072) -> fp16 Wt (3072 x 1024) -------
__global__ void transpose_w(const float* __restrict__ in, half_t* __restrict__ out) {
  __shared__ float tile[32][33];
  const int c0 = blockIdx.x * 32, r0 = blockIdx.y * 32;
  const int x = threadIdx.x, y = threadIdx.y;   // 32 x 8
  #pragma unroll
  for (int i = 0; i < 32; i += 8) tile[y + i][x] = in[(long)(r0 + y + i) * N3 + c0 + x];
  __syncthreads();
  #pragma unroll
  for (int i = 0; i < 32; i += 8)
    out[(long)(c0 + y + i) * DM + r0 + x] = (half_t)tile[x][y + i];
}

// ---- V transpose: Vb (M,1024) row-major -> Vt (B,H,64,S), both fp16 ----
__global__ void transpose_v(const half_t* __restrict__ vb, half_t* __restrict__ vt) {
  __shared__ half_t tile[32][33];
  const int b = blockIdx.z >> 4, h = blockIdx.z & 15;
  const int d0 = blockIdx.x * 32, s0 = blockIdx.y * 32;
  const int x = threadIdx.x, y = threadIdx.y;   // 32 x 8
  const half_t* ip = vb + (long)b * S * DM + h * HD;
  half_t* op = vt + (long)(b * NH + h) * HD * S;
  #pragma unroll
  for (int i = 0; i < 32; i += 8) tile[y + i][x] = ip[(long)(s0 + y + i) * DM + d0 + x];
  __syncthreads();
  #pragma unroll
  for (int i = 0; i < 32; i += 8) op[(long)(d0 + y + i) * S + s0 + x] = tile[x][y + i];
}

// ---- QKV GEMM: R7 body + XCD-locality swizzle (xcd owns 4-row M-strip) ----
// Q epilogue pre-scales by 0.125*log2(e) so attn softmax is a bare v_exp.
__global__ __launch_bounds__(256) void qkv_gemm(
    const half_t* __restrict__ A, const half_t* __restrict__ Bt,
    const float* __restrict__ qbias, const float* __restrict__ vbias,
    half_t* __restrict__ Qf, half_t* __restrict__ Kf, half_t* __restrict__ Vb)
{
  constexpr int BM = 128, BN = 128, BK = 32;
  __shared__ alignas(16) half_t As[BM * BK];   // 8 KB, lane-ordered (DMA layout)
  __shared__ alignas(16) half_t Bs[BN * BK];   // 8 KB
  const int t = threadIdx.x, lane = t & 63, wave = t >> 6;
  const int quad = lane >> 4, l16 = lane & 15;
  // swizzle: 768 blocks; xcd = id&7 gets m-strip [4*xcd,4*xcd+4), streams n
  const int id = blockIdx.x, xcd = id & 7, jj = id >> 3;
  const int m0 = (xcd * 4 + (jj & 3)) * BM;    // 32 m-blocks
  const int n0 = (jj >> 2) * BN;               // 24 n-blocks
  const int wm = (wave & 1) * 64, wn = (wave >> 1) * 64;

  const half_t* aP0 = A  + (long)(m0 + (t >> 2)) * DM + (t & 3) * 8;
  const half_t* aP1 = aP0 + (long)64 * DM;
  const half_t* bP0 = Bt + (long)(n0 + (t >> 2)) * DM + (t & 3) * 8;
  const half_t* bP1 = bP0 + (long)64 * DM;
  half_t* asW = As + wave * 512;
  half_t* bsW = Bs + wave * 512;

  f32x4 acc[4][4] = {};

  for (int k0 = 0; k0 < DM; k0 += BK) {
    __syncthreads();
    gl_lds16(aP0 + k0, asW);
    gl_lds16(aP1 + k0, asW + 2048);
    gl_lds16(bP0 + k0, bsW);
    gl_lds16(bP1 + k0, bsW + 2048);
    __builtin_amdgcn_s_waitcnt(0);
    __syncthreads();

    h8 af[4], bfr[4];
    #pragma unroll
    for (int i = 0; i < 4; i++) af[i]  = ld8h(&As[(wm + i * 16 + l16) * BK + quad * 8]);
    #pragma unroll
    for (int j = 0; j < 4; j++) bfr[j] = ld8h(&Bs[(wn + j * 16 + l16) * BK + quad * 8]);
    #pragma unroll
    for (int i = 0; i < 4; i++)
      #pragma unroll
      for (int j = 0; j < 4; j++)
        acc[i][j] = mfma16(af[i], bfr[j], acc[i][j]);
  }

  // epilogue: C layout col=l16 (n), row=quad*4+r (m). All stores coalesced.
  #pragma unroll
  for (int i = 0; i < 4; i++) {
    #pragma unroll
    for (int j = 0; j < 4; j++) {
      const int n = n0 + wn + j * 16 + l16;
      #pragma unroll
      for (int r = 0; r < 4; r++) {
        const long m = m0 + wm + i * 16 + quad * 4 + r;
        const float cv = acc[i][j][r];
        if (n < DM) {
          // 0.125 * log2(e): scores come out in log2 domain for bare v_exp
          Qf[m * DM + n] = (half_t)((cv + qbias[n]) * 0.1803368801f);
        } else if (n < 2 * DM) {
          Kf[m * DM + (n - DM)] = (half_t)cv;
        } else {
          const int nv = n - 2 * DM;
          Vb[m * DM + nv] = (half_t)(cv + vbias[nv]);   // row-major, coalesced
        }
      }
    }
  }
}

// ---- Flash attention v11: ZERO LDS, ZERO barriers, free-running waves ----
// R1-R4 evidence: attn invariant to blocks/LDS/barriers; per-CU DS pipe is
// saturated (12 b128 + 16 b64 + 384cy conflicts per wave-tile ~= epoch time).
// Fix: all MFMA fragments load DIRECTLY from global. Per-tile working set
// (8KB K + 8KB V) is L1-resident; the 4-wave duplication hits L1; K/V per
// (b,h) is L2-resident. K-frag rows consume full 128B lines; V-frag g-groups
// tile each 128B line. All 24 tile-loads issued up-front for deep MLP.
__global__ __launch_bounds__(256) void attn(
    const half_t* __restrict__ Qf, const half_t* __restrict__ Kf,
    const half_t* __restrict__ Vt, float* __restrict__ out)
{
  const int bh = blockIdx.y, b = bh >> 4, h = bh & 15;
  const int qt = blockIdx.x;                        // 16 tiles of 128 q rows
  const int t = threadIdx.x, lane = t & 63, wave = t >> 6;
  const int quad = lane >> 4, l16 = lane & 15;

  const long qrow0 = (long)b * S + qt * 128 + wave * 32;
  const half_t* qg = Qf + qrow0 * DM + h * HD;
  // per-lane fragment base pointers
  const half_t* kfb = Kf + ((long)b * S + l16) * DM + h * HD + quad * 8;  // + (k0+g*16)*DM (+32)
  const half_t* vfb = Vt + (long)bh * HD * S + (long)l16 * S + quad * 4;  // + (j*16)*S + k0 + g*16

  // Q B-frags (registers): B[k=d(quad*8+j)][n=q(l16)], per 16-row half qi
  h8 bq[2][2];
  #pragma unroll
  for (int qi = 0; qi < 2; qi++)
    #pragma unroll
    for (int dh = 0; dh < 2; dh++)
      bq[qi][dh] = ld8h(&qg[(long)(qi * 16 + l16) * DM + dh * 32 + quad * 8]);

  const f32x4 z4 = {0.f, 0.f, 0.f, 0.f};            // hoisted zero C-operand
  const h4 vones = {(half_t)1.f, (half_t)1.f, (half_t)1.f, (half_t)1.f};

  f32x4 O[2][4] = {};          // O[qi][j]: row=q(quad*4+r), col=d(j*16+l16)
  f32x4 lacc[2] = {};          // row-sum of P: lacc[qi][r] = denom for q=quad*4+r

  for (int kt = 0; kt < S / 64; ++kt) {
    const long k0 = (long)kt * 64;

    // issue ALL tile loads first (24 instrs, no dependencies -> deep MLP)
    h8 kf[4][2];               // K[key=g*16+l16][d=quad*8.. (+32)]
    #pragma unroll
    for (int g = 0; g < 4; g++) {
      kf[g][0] = ld8h(kfb + (k0 + g * 16) * DM);
      kf[g][1] = ld8h(kfb + (k0 + g * 16) * DM + 32);
    }
    h4 vf[4][4];               // V^T[d=j*16+l16][key=k0+g*16+quad*4..]
    #pragma unroll
    for (int j = 0; j < 4; j++)
      #pragma unroll
      for (int g = 0; g < 4; g++)
        vf[j][g] = *(const h4*)(vfb + (long)(j * 16) * S + k0 + g * 16);

    // QK^T: per g (16 keys), K frags shared across both qi halves.
    // Scores stay in registers as PV A-frags: pa[qi][g] (h4, k=quad*4+j).
    h4 pa[2][4];
    #pragma unroll
    for (int g = 0; g < 4; g++) {
      #pragma unroll
      for (int qi = 0; qi < 2; qi++) {
        f32x4 sc = mfma16(kf[g][0], bq[qi][0], z4);
        sc = mfma16(kf[g][1], bq[qi][1], sc);
        // Q pre-scaled by log2e: p = 2^sc (global shift dropped; softmax-invariant)
        h4 pk;
        #pragma unroll
        for (int r = 0; r < 4; r++) pk[r] = (half_t)ex2(sc[r]);
        pa[qi][g] = pk;
      }
    }

    // denominator: rowsum(P) via ones-MFMA. D[row=quad*4+r] = sum over 16 keys.
    #pragma unroll
    for (int g = 0; g < 4; g++) {
      lacc[0] = mfma16h(pa[0][g], vones, lacc[0]);
      lacc[1] = mfma16h(pa[1][g], vones, lacc[1]);
    }

    // PV via K=16 MFMA: B[k=key(quad*4+j)][n=d(l16)] from registers.
    #pragma unroll
    for (int j = 0; j < 4; j++) {
      #pragma unroll
      for (int g = 0; g < 4; g++) {
        O[0][j] = mfma16h(pa[0][g], vf[j][g], O[0][j]);
        O[1][j] = mfma16h(pa[1][g], vf[j][g], O[1][j]);
      }
    }
  }

  // store: lacc[qi][r] is the denominator for exactly the row this lane stores
  #pragma unroll
  for (int qi = 0; qi < 2; qi++) {
    #pragma unroll
    for (int r = 0; r < 4; r++) {
      const float linv = 1.f / lacc[qi][r];
      const long srow = qrow0 + qi * 16 + quad * 4 + r;
      #pragma unroll
      for (int j = 0; j < 4; j++)
        out[srow * DM + h * HD + j * 16 + l16] = O[qi][j][r] * linv;
    }
  }
}

extern "C" void kernel_launch(void* const* d_in, const int* in_sizes, int n_in,
                              void* d_out, int out_size, void* d_ws, size_t ws_size,
                              hipStream_t stream) {
  (void)in_sizes; (void)n_in; (void)out_size; (void)ws_size;
  const float* hidden = (const float*)d_in[0];   // fp32 (2,2048,1024)
  const float* W      = (const float*)d_in[1];   // fp32 (1024,3072)
  const float* qbias  = (const float*)d_in[2];   // fp32 zeros
  const float* vbias  = (const float*)d_in[3];
  float* out = (float*)d_out;                    // fp32 output (16 MB)

  half_t* ws = (half_t*)d_ws;                    // fp16 scratch, 38 MB (proven)
  half_t* Hb = ws;                               // 4096 x 1024
  half_t* Wt = Hb + M * DM;                      // 3072 x 1024
  half_t* Qf = Wt + (long)N3 * DM;               // 4096 x 1024 (pre-scaled, log2 dom)
  half_t* Kf = Qf + M * DM;                      // 4096 x 1024
  half_t* Vt = Kf + M * DM;                      // (B,H,64,S)

  half_t* Vb = (half_t*)d_out;                   // 8 MB row-major V staging in out
                                                 // (consumed by transpose_v before attn)

  convert_h<<<(int)(M * DM / (256 * 8)), 256, 0, stream>>>(hidden, Hb);
  transpose_w<<<dim3(N3 / 32, DM / 32), dim3(32, 8), 0, stream>>>(W, Wt);
  qkv_gemm<<<(N3 / 128) * (int)(M / 128), 256, 0, stream>>>(Hb, Wt, qbias, vbias, Qf, Kf, Vb);
  transpose_v<<<dim3(HD / 32, S / 32, NB * NH), dim3(32, 8), 0, stream>>>(Vb, Vt);
  attn<<<dim3(S / 128, NB * NH), 256, 0, stream>>>(Qf, Kf, Vt, out);
}

// Round 7
// 186.373 us; speedup vs baseline: 1.5963x; 1.5963x over previous
//
#include <hip/hip_runtime.h>
#include <hip/hip_bf16.h>

typedef _Float16 half_t;
typedef _Float16 h8 __attribute__((ext_vector_type(8)));   // MFMA A/B frag (4 VGPRs)
typedef _Float16 h4 __attribute__((ext_vector_type(4)));   // 8B chunk / K=16 frag
typedef _Float16 h2 __attribute__((ext_vector_type(2)));
typedef float f32x4 __attribute__((ext_vector_type(4)));   // MFMA C/D frag
typedef float f4 __attribute__((ext_vector_type(4)));

#define DEVI __device__ __forceinline__

constexpr int NB = 2;         // batch
constexpr int S  = 2048;      // seq len
constexpr int DM = 1024;      // model dim
constexpr int NH = 16;        // heads
constexpr int HD = 64;        // head dim
constexpr long M = (long)NB * S;   // 4096 tokens
constexpr int N3 = 3 * DM;         // 3072 qkv cols

DEVI f32x4 mfma16(h8 a, h8 b, f32x4 c) {
  return __builtin_amdgcn_mfma_f32_16x16x32_f16(a, b, c, 0, 0, 0);
}
DEVI f32x4 mfma16h(h4 a, h4 b, f32x4 c) {          // K=16 legacy shape
  return __builtin_amdgcn_mfma_f32_16x16x16f16(a, b, c, 0, 0, 0);
}
DEVI h8 ld8h(const half_t* p) { return *(const h8*)p; }

#if __has_builtin(__builtin_amdgcn_exp2f)
DEVI float ex2(float x) { return __builtin_amdgcn_exp2f(x); }
#else
DEVI float ex2(float x) { float r; asm("v_exp_f32 %0, %1" : "=v"(r) : "v"(x)); return r; }
#endif

// packed f32x2 -> f16x2 (v_cvt_pkrtz_f16_f32); builtin returns __fp16x2 -> bit-cast
DEVI h2 pk2(float a, float b) {
  auto r = __builtin_amdgcn_cvt_pkrtz(a, b);
  h2 o; __builtin_memcpy(&o, &r, sizeof(o)); return o;
}

DEVI void gl_lds16(const half_t* g, half_t* l) {
  __builtin_amdgcn_global_load_lds(
      (const __attribute__((address_space(1))) void*)g,
      (__attribute__((address_space(3))) void*)l, 16, 0, 0);
}

// ---- prep: fused convert_h (blocks 0..2047) + transpose_w (blocks 2048..5119) ----
__global__ void prep(const float* __restrict__ hidden, half_t* __restrict__ Hb,
                     const float* __restrict__ W, half_t* __restrict__ Wt) {
  __shared__ float tile[32][33];
  const int id = blockIdx.x, t = threadIdx.x;
  if (id < 2048) {             // H fp32 -> fp16 (4M elems, 8/thread)
    const long i = ((long)id * 256 + t) * 8;
    const f4 a = *(const f4*)(hidden + i), b = *(const f4*)(hidden + i + 4);
    h8 r;
    #pragma unroll
    for (int k = 0; k < 4; k++) { r[k] = (half_t)a[k]; r[4 + k] = (half_t)b[k]; }
    *(h8*)(Hb + i) = r;
  } else {                     // W transpose+convert: (1024 x 3072) -> (3072 x 1024)
    const int id2 = id - 2048;
    const int c0 = (id2 % 96) * 32, r0 = (id2 / 96) * 32;
    const int x = t & 31, y = t >> 5;   // 32 x 8
    #pragma unroll
    for (int i = 0; i < 32; i += 8) tile[y + i][x] = W[(long)(r0 + y + i) * N3 + c0 + x];
    __syncthreads();
    #pragma unroll
    for (int i = 0; i < 32; i += 8)
      Wt[(long)(c0 + y + i) * DM + r0 + x] = (half_t)tile[x][y + i];
  }
}

// ---- V transpose: Vb (M,1024) row-major -> Vt (B,H,64,S), both fp16 ----
__global__ void transpose_v(const half_t* __restrict__ vb, half_t* __restrict__ vt) {
  __shared__ half_t tile[32][33];
  const int b = blockIdx.z >> 4, h = blockIdx.z & 15;
  const int d0 = blockIdx.x * 32, s0 = blockIdx.y * 32;
  const int x = threadIdx.x, y = threadIdx.y;   // 32 x 8
  const half_t* ip = vb + (long)b * S * DM + h * HD;
  half_t* op = vt + (long)(b * NH + h) * HD * S;
  #pragma unroll
  for (int i = 0; i < 32; i += 8) tile[y + i][x] = ip[(long)(s0 + y + i) * DM + d0 + x];
  __syncthreads();
  #pragma unroll
  for (int i = 0; i < 32; i += 8) op[(long)(d0 + y + i) * S + s0 + x] = tile[x][y + i];
}

// ---- QKV GEMM: R7 body + XCD-locality swizzle (xcd owns 4-row M-strip) ----
// Q epilogue pre-scales by 0.125*log2(e) so attn softmax is a bare v_exp.
__global__ __launch_bounds__(256) void qkv_gemm(
    const half_t* __restrict__ A, const half_t* __restrict__ Bt,
    const float* __restrict__ qbias, const float* __restrict__ vbias,
    half_t* __restrict__ Qf, half_t* __restrict__ Kf, half_t* __restrict__ Vb)
{
  constexpr int BM = 128, BN = 128, BK = 32;
  __shared__ alignas(16) half_t As[BM * BK];   // 8 KB, lane-ordered (DMA layout)
  __shared__ alignas(16) half_t Bs[BN * BK];   // 8 KB
  const int t = threadIdx.x, lane = t & 63, wave = t >> 6;
  const int quad = lane >> 4, l16 = lane & 15;
  // swizzle: 768 blocks; xcd = id&7 gets m-strip [4*xcd,4*xcd+4), streams n
  const int id = blockIdx.x, xcd = id & 7, jj = id >> 3;
  const int m0 = (xcd * 4 + (jj & 3)) * BM;    // 32 m-blocks
  const int n0 = (jj >> 2) * BN;               // 24 n-blocks
  const int wm = (wave & 1) * 64, wn = (wave >> 1) * 64;

  const half_t* aP0 = A  + (long)(m0 + (t >> 2)) * DM + (t & 3) * 8;
  const half_t* aP1 = aP0 + (long)64 * DM;
  const half_t* bP0 = Bt + (long)(n0 + (t >> 2)) * DM + (t & 3) * 8;
  const half_t* bP1 = bP0 + (long)64 * DM;
  half_t* asW = As + wave * 512;
  half_t* bsW = Bs + wave * 512;

  f32x4 acc[4][4] = {};

  for (int k0 = 0; k0 < DM; k0 += BK) {
    __syncthreads();
    gl_lds16(aP0 + k0, asW);
    gl_lds16(aP1 + k0, asW + 2048);
    gl_lds16(bP0 + k0, bsW);
    gl_lds16(bP1 + k0, bsW + 2048);
    __builtin_amdgcn_s_waitcnt(0);
    __syncthreads();

    h8 af[4], bfr[4];
    #pragma unroll
    for (int i = 0; i < 4; i++) af[i]  = ld8h(&As[(wm + i * 16 + l16) * BK + quad * 8]);
    #pragma unroll
    for (int j = 0; j < 4; j++) bfr[j] = ld8h(&Bs[(wn + j * 16 + l16) * BK + quad * 8]);
    #pragma unroll
    for (int i = 0; i < 4; i++)
      #pragma unroll
      for (int j = 0; j < 4; j++)
        acc[i][j] = mfma16(af[i], bfr[j], acc[i][j]);
  }

  // epilogue: C layout col=l16 (n), row=quad*4+r (m). All stores coalesced.
  #pragma unroll
  for (int i = 0; i < 4; i++) {
    #pragma unroll
    for (int j = 0; j < 4; j++) {
      const int n = n0 + wn + j * 16 + l16;
      #pragma unroll
      for (int r = 0; r < 4; r++) {
        const long m = m0 + wm + i * 16 + quad * 4 + r;
        const float cv = acc[i][j][r];
        if (n < DM) {
          // 0.125 * log2(e): scores come out in log2 domain for bare v_exp
          Qf[m * DM + n] = (half_t)((cv + qbias[n]) * 0.1803368801f);
        } else if (n < 2 * DM) {
          Kf[m * DM + (n - DM)] = (half_t)cv;
        } else {
          const int nv = n - 2 * DM;
          Vb[m * DM + nv] = (half_t)(cv + vbias[nv]);   // row-major, coalesced
        }
      }
    }
  }
}

// ---- Flash attention v12: q-split for TLP. 16 q/wave, 64 q/block,
// grid = 32 q-tiles x 32 bh = 1024 blocks -> 4 blocks/CU = 4 waves/SIMD
// (R0-R5 evidence: all pipes <=40% at 2 waves/SIMD, invariant to per-wave
// inst count => latency-bound, needs TLP). v10 inner structure kept:
// LDS staging + reg-P K=16 PV + ones-MFMA lsum + bare v_exp + cvt_pkrtz.
__global__ __launch_bounds__(256) void attn(
    const half_t* __restrict__ Qf, const half_t* __restrict__ Kf,
    const half_t* __restrict__ Vt, float* __restrict__ out)
{
  constexpr int LK = 72, LV = 72;                   // 144B rows (16B-aligned)
  __shared__ alignas(16) half_t Ks[64 * LK];        // [key][d]  9 KB
  __shared__ alignas(16) half_t Vs[64 * LV];        // [d][key]  9 KB

  const int bh = blockIdx.y, b = bh >> 4, h = bh & 15;
  const int qt = blockIdx.x;                        // 32 tiles of 64 q rows
  const int t = threadIdx.x, lane = t & 63, wave = t >> 6;
  const int quad = lane >> 4, l16 = lane & 15;

  const long qrow0 = (long)b * S + qt * 64 + wave * 16;
  const half_t* qg = Qf + qrow0 * DM + h * HD;
  const half_t* kg = Kf + (long)b * S * DM + h * HD;
  const half_t* vg = Vt + (long)bh * HD * S;

  // Q B-frags (registers): B[k=d(quad*8+j)][n=q(l16)]
  h8 bq[2];
  #pragma unroll
  for (int dh = 0; dh < 2; dh++)
    bq[dh] = ld8h(&qg[(long)l16 * DM + dh * 32 + quad * 8]);

  // staging map (256 thr, 2 chunks each): row = idx>>3, ch = (idx&7)*8
  const int r0s = t >> 3, c0s = (t & 7) * 8;
  const int r1s = 32 + r0s;
  h8 kreg[2], vreg[2];
  kreg[0] = ld8h(&kg[(long)r0s * DM + c0s]);
  kreg[1] = ld8h(&kg[(long)r1s * DM + c0s]);
  vreg[0] = ld8h(&vg[(long)r0s * S + c0s]);
  vreg[1] = ld8h(&vg[(long)r1s * S + c0s]);

  const f32x4 z4 = {0.f, 0.f, 0.f, 0.f};            // hoisted zero C-operand
  const h4 vones = {(half_t)1.f, (half_t)1.f, (half_t)1.f, (half_t)1.f};

  f32x4 O[4] = {};             // O[j]: row=q(quad*4+r), col=d(j*16+l16)
  f32x4 lacc = {};             // row-sum of P: lacc[r] = denom for q=quad*4+r

  for (int kt = 0; kt < S / 64; ++kt) {
    __syncthreads();   // prior iter's Ks/Vs reads done
    *(h8*)&Ks[r0s * LK + c0s] = kreg[0];
    *(h8*)&Ks[r1s * LK + c0s] = kreg[1];
    *(h8*)&Vs[r0s * LV + c0s] = vreg[0];
    *(h8*)&Vs[r1s * LV + c0s] = vreg[1];
    __syncthreads();   // tiles ready

    if (kt < S / 64 - 1) {     // prefetch next tile; consumed at next iter's write
      const long ko = (long)(kt + 1) * 64;
      kreg[0] = ld8h(&kg[(ko + r0s) * DM + c0s]);
      kreg[1] = ld8h(&kg[(ko + r1s) * DM + c0s]);
      vreg[0] = ld8h(&vg[(long)r0s * S + ko + c0s]);
      vreg[1] = ld8h(&vg[(long)r1s * S + ko + c0s]);
    }

    // QK^T per g (16 keys). Scores stay in registers as PV A-frags pa[g].
    h4 pa[4];
    #pragma unroll
    for (int g = 0; g < 4; g++) {
      const h8 kf0 = ld8h(&Ks[(g * 16 + l16) * LK + quad * 8]);
      const h8 kf1 = ld8h(&Ks[(g * 16 + l16) * LK + 32 + quad * 8]);
      f32x4 sc = mfma16(kf0, bq[0], z4);
      sc = mfma16(kf1, bq[1], sc);
      // Q pre-scaled by log2e: p = 2^sc (global shift dropped; softmax-invariant)
      const h2 lo = pk2(ex2(sc[0]), ex2(sc[1]));
      const h2 hi = pk2(ex2(sc[2]), ex2(sc[3]));
      union { h4 v; h2 p[2]; } u; u.p[0] = lo; u.p[1] = hi;
      pa[g] = u.v;
    }

    // denominator: rowsum(P) via ones-MFMA. D[row=quad*4+r] = sum over 16 keys.
    #pragma unroll
    for (int g = 0; g < 4; g++) lacc = mfma16h(pa[g], vones, lacc);

    // PV via K=16 MFMA: B[k=key(quad*4+j)][n=d(l16)] read as b64 from Vs[d][key].
    #pragma unroll
    for (int j = 0; j < 4; j++) {
      #pragma unroll
      for (int g = 0; g < 4; g++) {
        const h4 vf = *(const h4*)&Vs[(j * 16 + l16) * LV + g * 16 + quad * 4];
        O[j] = mfma16h(pa[g], vf, O[j]);
      }
    }
  }

  // store: lacc[r] is the denominator for exactly the row this lane stores
  #pragma unroll
  for (int r = 0; r < 4; r++) {
    const float linv = 1.f / lacc[r];
    const long srow = qrow0 + quad * 4 + r;
    #pragma unroll
    for (int j = 0; j < 4; j++)
      out[srow * DM + h * HD + j * 16 + l16] = O[j][r] * linv;
  }
}

extern "C" void kernel_launch(void* const* d_in, const int* in_sizes, int n_in,
                              void* d_out, int out_size, void* d_ws, size_t ws_size,
                              hipStream_t stream) {
  (void)in_sizes; (void)n_in; (void)out_size; (void)ws_size;
  const float* hidden = (const float*)d_in[0];   // fp32 (2,2048,1024)
  const float* W      = (const float*)d_in[1];   // fp32 (1024,3072)
  const float* qbias  = (const float*)d_in[2];   // fp32 zeros
  const float* vbias  = (const float*)d_in[3];
  float* out = (float*)d_out;                    // fp32 output (16 MB)

  half_t* ws = (half_t*)d_ws;                    // fp16 scratch, 38 MB (proven)
  half_t* Hb = ws;                               // 4096 x 1024
  half_t* Wt = Hb + M * DM;                      // 3072 x 1024
  half_t* Qf = Wt + (long)N3 * DM;               // 4096 x 1024 (pre-scaled, log2 dom)
  half_t* Kf = Qf + M * DM;                      // 4096 x 1024
  half_t* Vt = Kf + M * DM;                      // (B,H,64,S)

  half_t* Vb = (half_t*)d_out;                   // 8 MB row-major V staging in out
                                                 // (consumed by transpose_v before attn)

  prep<<<2048 + 3072, 256, 0, stream>>>(hidden, Hb, W, Wt);
  qkv_gemm<<<(N3 / 128) * (int)(M / 128), 256, 0, stream>>>(Hb, Wt, qbias, vbias, Qf, Kf, Vb);
  transpose_v<<<dim3(HD / 32, S / 32, NB * NH), dim3(32, 8), 0, stream>>>(Vb, Vt);
  attn<<<dim3(S / 64, NB * NH), 256, 0, stream>>>(Qf, Kf, Vt, out);
}

// Round 8
// 171.041 us; speedup vs baseline: 1.7394x; 1.0896x over previous
//
#include <hip/hip_runtime.h>
#include <hip/hip_bf16.h>

typedef _Float16 half_t;
typedef _Float16 h8 __attribute__((ext_vector_type(8)));   // MFMA A/B frag (4 VGPRs)
typedef _Float16 h4 __attribute__((ext_vector_type(4)));   // 8B chunk / K=16 frag
typedef _Float16 h2 __attribute__((ext_vector_type(2)));
typedef float f32x4 __attribute__((ext_vector_type(4)));   // MFMA C/D frag
typedef float f4 __attribute__((ext_vector_type(4)));

#define DEVI __device__ __forceinline__

constexpr int NB = 2;         // batch
constexpr int S  = 2048;      // seq len
constexpr int DM = 1024;      // model dim
constexpr int NH = 16;        // heads
constexpr int HD = 64;        // head dim
constexpr long M = (long)NB * S;   // 4096 tokens
constexpr int N3 = 3 * DM;         // 3072 qkv cols

DEVI f32x4 mfma16(h8 a, h8 b, f32x4 c) {
  return __builtin_amdgcn_mfma_f32_16x16x32_f16(a, b, c, 0, 0, 0);
}
DEVI f32x4 mfma16h(h4 a, h4 b, f32x4 c) {          // K=16 legacy shape
  return __builtin_amdgcn_mfma_f32_16x16x16f16(a, b, c, 0, 0, 0);
}
DEVI h8 ld8h(const half_t* p) { return *(const h8*)p; }

#if __has_builtin(__builtin_amdgcn_exp2f)
DEVI float ex2(float x) { return __builtin_amdgcn_exp2f(x); }
#else
DEVI float ex2(float x) { float r; asm("v_exp_f32 %0, %1" : "=v"(r) : "v"(x)); return r; }
#endif

// packed f32x2 -> f16x2 (v_cvt_pkrtz_f16_f32); builtin returns __fp16x2 -> bit-cast
DEVI h2 pk2(float a, float b) {
  auto r = __builtin_amdgcn_cvt_pkrtz(a, b);
  h2 o; __builtin_memcpy(&o, &r, sizeof(o)); return o;
}

DEVI void gl_lds16(const half_t* g, half_t* l) {
  __builtin_amdgcn_global_load_lds(
      (const __attribute__((address_space(1))) void*)g,
      (__attribute__((address_space(3))) void*)l, 16, 0, 0);
}

// ---- prep: fused convert_h (blocks 0..2047) + transpose_w (blocks 2048..5119) ----
__global__ void prep(const float* __restrict__ hidden, half_t* __restrict__ Hb,
                     const float* __restrict__ W, half_t* __restrict__ Wt) {
  __shared__ float tile[32][33];
  const int id = blockIdx.x, t = threadIdx.x;
  if (id < 2048) {             // H fp32 -> fp16 (4M elems, 8/thread)
    const long i = ((long)id * 256 + t) * 8;
    const f4 a = *(const f4*)(hidden + i), b = *(const f4*)(hidden + i + 4);
    h8 r;
    #pragma unroll
    for (int k = 0; k < 4; k++) { r[k] = (half_t)a[k]; r[4 + k] = (half_t)b[k]; }
    *(h8*)(Hb + i) = r;
  } else {                     // W transpose+convert: (1024 x 3072) -> (3072 x 1024)
    const int id2 = id - 2048;
    const int c0 = (id2 % 96) * 32, r0 = (id2 / 96) * 32;
    const int x = t & 31, y = t >> 5;   // 32 x 8
    #pragma unroll
    for (int i = 0; i < 32; i += 8) tile[y + i][x] = W[(long)(r0 + y + i) * N3 + c0 + x];
    __syncthreads();
    #pragma unroll
    for (int i = 0; i < 32; i += 8)
      Wt[(long)(c0 + y + i) * DM + r0 + x] = (half_t)tile[x][y + i];
  }
}

// ---- QKV GEMM: R7 body + XCD swizzle + FUSED V-transpose epilogue ----
// Q pre-scaled by 0.125*log2(e) (bare v_exp softmax). V written directly in
// (B,H,64,S) layout as packed 8B stores of 4 consecutive s -> transpose_v gone.
__global__ __launch_bounds__(256) void qkv_gemm(
    const half_t* __restrict__ A, const half_t* __restrict__ Bt,
    const float* __restrict__ qbias, const float* __restrict__ vbias,
    half_t* __restrict__ Qf, half_t* __restrict__ Kf, half_t* __restrict__ Vt)
{
  constexpr int BM = 128, BN = 128, BK = 32;
  __shared__ alignas(16) half_t As[BM * BK];   // 8 KB, lane-ordered (DMA layout)
  __shared__ alignas(16) half_t Bs[BN * BK];   // 8 KB
  const int t = threadIdx.x, lane = t & 63, wave = t >> 6;
  const int quad = lane >> 4, l16 = lane & 15;
  // swizzle: 768 blocks; xcd = id&7 gets m-strip [4*xcd,4*xcd+4), streams n
  const int id = blockIdx.x, xcd = id & 7, jj = id >> 3;
  const int m0 = (xcd * 4 + (jj & 3)) * BM;    // 32 m-blocks
  const int n0 = (jj >> 2) * BN;               // 24 n-blocks
  const int wm = (wave & 1) * 64, wn = (wave >> 1) * 64;

  const half_t* aP0 = A  + (long)(m0 + (t >> 2)) * DM + (t & 3) * 8;
  const half_t* aP1 = aP0 + (long)64 * DM;
  const half_t* bP0 = Bt + (long)(n0 + (t >> 2)) * DM + (t & 3) * 8;
  const half_t* bP1 = bP0 + (long)64 * DM;
  half_t* asW = As + wave * 512;
  half_t* bsW = Bs + wave * 512;

  f32x4 acc[4][4] = {};

  for (int k0 = 0; k0 < DM; k0 += BK) {
    __syncthreads();
    gl_lds16(aP0 + k0, asW);
    gl_lds16(aP1 + k0, asW + 2048);
    gl_lds16(bP0 + k0, bsW);
    gl_lds16(bP1 + k0, bsW + 2048);
    __builtin_amdgcn_s_waitcnt(0);
    __syncthreads();

    h8 af[4], bfr[4];
    #pragma unroll
    for (int i = 0; i < 4; i++) af[i]  = ld8h(&As[(wm + i * 16 + l16) * BK + quad * 8]);
    #pragma unroll
    for (int j = 0; j < 4; j++) bfr[j] = ld8h(&Bs[(wn + j * 16 + l16) * BK + quad * 8]);
    #pragma unroll
    for (int i = 0; i < 4; i++)
      #pragma unroll
      for (int j = 0; j < 4; j++)
        acc[i][j] = mfma16(af[i], bfr[j], acc[i][j]);
  }

  // epilogue: class (Q/K/V) is uniform per block (n-range within one 1024-band)
  if (n0 < 2 * DM) {
    #pragma unroll
    for (int i = 0; i < 4; i++) {
      #pragma unroll
      for (int j = 0; j < 4; j++) {
        const int n = n0 + wn + j * 16 + l16;
        #pragma unroll
        for (int r = 0; r < 4; r++) {
          const long m = m0 + wm + i * 16 + quad * 4 + r;
          const float cv = acc[i][j][r];
          if (n < DM) {
            // 0.125 * log2(e): scores come out in log2 domain for bare v_exp
            Qf[m * DM + n] = (half_t)((cv + qbias[n]) * 0.1803368801f);
          } else {
            Kf[m * DM + (n - DM)] = (half_t)cv;
          }
        }
      }
    }
  } else {
    // V fused transpose: per (i,j), 4 consecutive s at fixed d -> one 8B store
    const int dBase = n0 + wn - 2 * DM;          // + j*16 + l16
    #pragma unroll
    for (int i = 0; i < 4; i++) {
      const long mb = m0 + wm + i * 16 + quad * 4;   // 4 consecutive tokens
      const int bb = (int)(mb >> 11);                // batch (2048 rows each)
      const int ss = (int)(mb & (S - 1));
      #pragma unroll
      for (int j = 0; j < 4; j++) {
        const int dd = dBase + j * 16 + l16;         // 0..1023
        const float vb4 = vbias[dd];
        h4 vv;
        #pragma unroll
        for (int r = 0; r < 4; r++) vv[r] = (half_t)(acc[i][j][r] + vb4);
        *(h4*)&Vt[(((long)bb * NH + (dd >> 6)) * HD + (dd & 63)) * S + ss] = vv;
      }
    }
  }
}

// ---- Flash attention v13: in-block KV-split for TLP without DS inflation ----
// 8 waves/block (512 thr): waves 0-3 do keys [0,1024), waves 4-7 keys
// [1024,2048) for the SAME 128 q rows; each half stages its own Ks/Vs.
// Per-wave structure = proven v10 (32q/wave, reg-P K=16 PV, ones-MFMA lsum,
// bare v_exp). Grid 512 blocks -> 2 blocks/CU -> 4 waves/SIMD (was 2), with
// per-CU DS traffic per tile IDENTICAL to v10 (R7 falsified 16q/wave: 2x DS).
// Partials merge through a 33 KB LDS exchange (no merge kernel, no extra HBM);
// both halves use shift-free 2^sc so (O, lsum) partials add exactly.
__global__ __launch_bounds__(512) void attn(
    const half_t* __restrict__ Qf, const half_t* __restrict__ Kf,
    const half_t* __restrict__ Vt, float* __restrict__ out)
{
  constexpr int LK = 72, LV = 72;                   // 144B rows (16B-aligned)
  __shared__ alignas(16) half_t smem[2 * 64 * LK + 2 * 64 * LV];  // 36.9 KB
  half_t* const KsB = smem;                         // [kvh][64*LK]
  half_t* const VsB = smem + 2 * 64 * LK;           // [kvh][64*LV]

  const int bh = blockIdx.y, b = bh >> 4, h = bh & 15;
  const int qt = blockIdx.x;                        // 16 tiles of 128 q rows
  const int t = threadIdx.x, lane = t & 63, wave = t >> 6;
  const int w4 = wave & 3, kvh = wave >> 2;         // q-wave, kv-half
  const int quad = lane >> 4, l16 = lane & 15;

  const long qrow0 = (long)b * S + qt * 128 + w4 * 32;
  const half_t* qg = Qf + qrow0 * DM + h * HD;
  const long kb0 = (long)kvh * (S / 2);             // first key of this half
  const half_t* kg = Kf + ((long)b * S + kb0) * DM + h * HD;
  const half_t* vg = Vt + (long)bh * HD * S + kb0;  // column offset kb0

  // Q B-frags (registers): B[k=d(quad*8+j)][n=q(l16)], per 16-row half qi
  h8 bq[2][2];
  #pragma unroll
  for (int qi = 0; qi < 2; qi++)
    #pragma unroll
    for (int dh = 0; dh < 2; dh++)
      bq[qi][dh] = ld8h(&qg[(long)(qi * 16 + l16) * DM + dh * 32 + quad * 8]);

  // staging map per 4-wave group (256 thr, 2 chunks each)
  const int tg = t & 255;
  const int r0s = tg >> 3, c0s = (tg & 7) * 8;
  const int r1s = 32 + r0s;
  half_t* const ksW = KsB + kvh * (64 * LK);
  half_t* const vsW = VsB + kvh * (64 * LV);
  h8 kreg[2], vreg[2];
  kreg[0] = ld8h(&kg[(long)r0s * DM + c0s]);
  kreg[1] = ld8h(&kg[(long)r1s * DM + c0s]);
  vreg[0] = ld8h(&vg[(long)r0s * S + c0s]);
  vreg[1] = ld8h(&vg[(long)r1s * S + c0s]);

  const f32x4 z4 = {0.f, 0.f, 0.f, 0.f};            // hoisted zero C-operand
  const h4 vones = {(half_t)1.f, (half_t)1.f, (half_t)1.f, (half_t)1.f};

  f32x4 O[2][4] = {};          // O[qi][j]: row=q(quad*4+r), col=d(j*16+l16)
  f32x4 lacc[2] = {};          // row-sum of P (l16-replicated): lacc[qi][r]

  constexpr int NT = (S / 2) / 64;                  // 16 tiles per half
  for (int kt = 0; kt < NT; ++kt) {
    __syncthreads();   // prior iter's Ks/Vs reads done (all 8 waves)
    *(h8*)&ksW[r0s * LK + c0s] = kreg[0];
    *(h8*)&ksW[r1s * LK + c0s] = kreg[1];
    *(h8*)&vsW[r0s * LV + c0s] = vreg[0];
    *(h8*)&vsW[r1s * LV + c0s] = vreg[1];
    __syncthreads();   // tiles ready

    if (kt < NT - 1) {         // prefetch next tile; consumed at next iter's write
      const long ko = (long)(kt + 1) * 64;
      kreg[0] = ld8h(&kg[(ko + r0s) * DM + c0s]);
      kreg[1] = ld8h(&kg[(ko + r1s) * DM + c0s]);
      vreg[0] = ld8h(&vg[(long)r0s * S + ko + c0s]);
      vreg[1] = ld8h(&vg[(long)r1s * S + ko + c0s]);
    }

    // QK^T: per g (16 keys), K frags shared across both qi halves.
    h4 pa[2][4];
    #pragma unroll
    for (int g = 0; g < 4; g++) {
      const h8 kf0 = ld8h(&ksW[(g * 16 + l16) * LK + quad * 8]);
      const h8 kf1 = ld8h(&ksW[(g * 16 + l16) * LK + 32 + quad * 8]);
      #pragma unroll
      for (int qi = 0; qi < 2; qi++) {
        f32x4 sc = mfma16(kf0, bq[qi][0], z4);
        sc = mfma16(kf1, bq[qi][1], sc);
        // Q pre-scaled by log2e: p = 2^sc (softmax-invariant global shift dropped)
        const h2 lo = pk2(ex2(sc[0]), ex2(sc[1]));
        const h2 hi = pk2(ex2(sc[2]), ex2(sc[3]));
        union { h4 v; h2 p[2]; } u; u.p[0] = lo; u.p[1] = hi;
        pa[qi][g] = u.v;
      }
    }

    // denominator: rowsum(P) via ones-MFMA. D[row=quad*4+r] = sum over 16 keys.
    #pragma unroll
    for (int g = 0; g < 4; g++) {
      lacc[0] = mfma16h(pa[0][g], vones, lacc[0]);
      lacc[1] = mfma16h(pa[1][g], vones, lacc[1]);
    }

    // PV via K=16 MFMA: B[k=key(quad*4+j)][n=d(l16)] read as b64 from Vs[d][key].
    #pragma unroll
    for (int j = 0; j < 4; j++) {
      #pragma unroll
      for (int g = 0; g < 4; g++) {
        const h4 vf = *(const h4*)&vsW[(j * 16 + l16) * LV + g * 16 + quad * 4];
        O[0][j] = mfma16h(pa[0][g], vf, O[0][j]);
        O[1][j] = mfma16h(pa[1][g], vf, O[1][j]);
      }
    }
  }

  // ---- merge the two kv-halves through LDS (33 KB <= 36.9 KB smem alias) ----
  __syncthreads();             // all waves done reading Ks/Vs
  float* const xb = (float*)smem;        // O exchange: [w4][qi][j][lane] f32x4
  float* const xl = xb + 8192;           // lacc exchange: [w4][qi][16] (quad*4+r)
  if (kvh) {
    #pragma unroll
    for (int qi = 0; qi < 2; qi++) {
      #pragma unroll
      for (int j = 0; j < 4; j++)
        *(f4*)&xb[(((w4 * 2 + qi) * 4 + j) * 64 + lane) * 4] = O[qi][j];
      if (l16 == 0) {          // lacc is l16-replicated: one lane per quad writes
        #pragma unroll
        for (int r = 0; r < 4; r++)
          xl[(w4 * 2 + qi) * 16 + quad * 4 + r] = lacc[qi][r];
      }
    }
  }
  __syncthreads();
  if (!kvh) {
    #pragma unroll
    for (int qi = 0; qi < 2; qi++) {
      #pragma unroll
      for (int j = 0; j < 4; j++)
        O[qi][j] += *(const f4*)&xb[(((w4 * 2 + qi) * 4 + j) * 64 + lane) * 4];
      #pragma unroll
      for (int r = 0; r < 4; r++) {
        const float linv = 1.f / (lacc[qi][r] + xl[(w4 * 2 + qi) * 16 + quad * 4 + r]);
        const long srow = qrow0 + qi * 16 + quad * 4 + r;
        #pragma unroll
        for (int j = 0; j < 4; j++)
          out[srow * DM + h * HD + j * 16 + l16] = O[qi][j][r] * linv;
      }
    }
  }
}

extern "C" void kernel_launch(void* const* d_in, const int* in_sizes, int n_in,
                              void* d_out, int out_size, void* d_ws, size_t ws_size,
                              hipStream_t stream) {
  (void)in_sizes; (void)n_in; (void)out_size; (void)ws_size;
  const float* hidden = (const float*)d_in[0];   // fp32 (2,2048,1024)
  const float* W      = (const float*)d_in[1];   // fp32 (1024,3072)
  const float* qbias  = (const float*)d_in[2];   // fp32 zeros
  const float* vbias  = (const float*)d_in[3];
  float* out = (float*)d_out;                    // fp32 output (16 MB)

  half_t* ws = (half_t*)d_ws;                    // fp16 scratch, 38 MB (proven)
  half_t* Hb = ws;                               // 4096 x 1024
  half_t* Wt = Hb + M * DM;                      // 3072 x 1024
  half_t* Qf = Wt + (long)N3 * DM;               // 4096 x 1024 (pre-scaled, log2 dom)
  half_t* Kf = Qf + M * DM;                      // 4096 x 1024
  half_t* Vt = Kf + M * DM;                      // (B,H,64,S) -- written by qkv_gemm

  prep<<<2048 + 3072, 256, 0, stream>>>(hidden, Hb, W, Wt);
  qkv_gemm<<<(N3 / 128) * (int)(M / 128), 256, 0, stream>>>(Hb, Wt, qbias, vbias, Qf, Kf, Vt);
  attn<<<dim3(S / 128, NB * NH), 512, 0, stream>>>(Qf, Kf, Vt, out);
}